// Round 13
// baseline (1468.391 us; speedup 1.0000x reference)
//
#include <hip/hip_runtime.h>
#include <hip/hip_bf16.h>

#define NN 50000
#define NE 1000000
#define NF 32
#define ED 16
#define HD 64
#define BN_EPS 1e-5f

typedef unsigned short u16;
typedef __attribute__((ext_vector_type(8))) short bf16x8;
typedef __attribute__((ext_vector_type(4))) float f32x4;

// wave-level LDS fence: ds_writes complete + no compiler reordering (rule #18)
#define WAVE_SYNC() do { \
    asm volatile("s_waitcnt lgkmcnt(0)" ::: "memory"); \
    __builtin_amdgcn_sched_barrier(0); \
} while (0)

__device__ __forceinline__ u16 f2b(float x)
{
    __hip_bfloat16 b = __float2bfloat16(x);
    u16 u; __builtin_memcpy(&u, &b, 2); return u;
}

// pack 8 consecutive f32 -> bf16x8 fragment (in registers)
__device__ __forceinline__ bf16x8 pack8(const float* __restrict__ p)
{
    float4 v0 = ((const float4*)p)[0];
    float4 v1 = ((const float4*)p)[1];
    union { uint u[4]; bf16x8 v; } r;
    r.u[0] = (uint)f2b(v0.x) | ((uint)f2b(v0.y) << 16);
    r.u[1] = (uint)f2b(v0.z) | ((uint)f2b(v0.w) << 16);
    r.u[2] = (uint)f2b(v1.x) | ((uint)f2b(v1.y) << 16);
    r.u[3] = (uint)f2b(v1.z) | ((uint)f2b(v1.w) << 16);
    return r.v;
}

// ---------------- diag: fill an f32 region with a sentinel constant
__global__ __launch_bounds__(256) void k_fill(float* p, float v, size_t n)
{
    size_t i = (size_t)blockIdx.x * 256 + threadIdx.x;
    if (i < n) p[i] = v;
}

// rank-4 update: o += t * W[0:4][:]  (weights wave-uniform)
__device__ __forceinline__ void gemm4(float (&o)[HD], float4 t, const float* __restrict__ Wr)
{
    #pragma unroll
    for (int f = 0; f < HD; f++) o[f] = fmaf(t.x, Wr[f], o[f]);
    #pragma unroll
    for (int f = 0; f < HD; f++) o[f] = fmaf(t.y, Wr[HD + f], o[f]);
    #pragma unroll
    for (int f = 0; f < HD; f++) o[f] = fmaf(t.z, Wr[2 * HD + f], o[f]);
    #pragma unroll
    for (int f = 0; f < HD; f++) o[f] = fmaf(t.w, Wr[3 * HD + f], o[f]);
}

// ---------------- prep: W1[l][k][f] (f32) -> w1t[l][f][k] (bf16), k=0..191
__global__ __launch_bounds__(256) void k_prep_w1(const float* __restrict__ W, u16* __restrict__ out)
{
    int idx = blockIdx.x * 256 + threadIdx.x;
    if (idx >= 2 * 192 * HD) return;
    int l = idx / (192 * HD), r = idx % (192 * HD), k = r / HD, f = r % HD;
    out[l * 192 * HD + f * 192 + k] = f2b(W[idx]);
}
// ---------------- prep: 2 layers of [64][64] (k,f) -> (f,k) bf16
__global__ __launch_bounds__(256) void k_prep_w64(const float* __restrict__ W, u16* __restrict__ out)
{
    int idx = blockIdx.x * 256 + threadIdx.x;
    if (idx >= 2 * HD * HD) return;
    int l = idx / (HD * HD), r = idx % (HD * HD), k = r / HD, f = r % HD;
    out[l * HD * HD + f * HD + k] = f2b(W[idx]);
}

// ---------------- K1: h = x @ node_W + node_b  (wave per node, K=32 via shfl)
__global__ __launch_bounds__(256) void k_node_proj(
    const float* __restrict__ x, const float* __restrict__ W,
    const float* __restrict__ b, float* __restrict__ h)
{
    __shared__ float sW[NF * HD];   // 8 KB
    for (int t = threadIdx.x; t < NF * HD; t += 256) sW[t] = W[t];
    __syncthreads();
    int lane = threadIdx.x & 63, wv = threadIdx.x >> 6;
    int n = blockIdx.x * 4 + wv;
    if (n >= NN) return;
    float a = (lane < NF) ? x[(size_t)n * NF + lane] : 0.f;
    float acc = b[lane];
    #pragma unroll
    for (int k = 0; k < NF; k++) acc = fmaf(__shfl(a, k), sW[k * HD + lane], acc);
    h[(size_t)n * HD + lane] = acc;
}

// ---------------- K2: ea = edge_attr @ edge_W + edge_b  (thread per edge)
__global__ __launch_bounds__(256) void k_edge_proj(
    const float* __restrict__ attr, const float* __restrict__ W,
    const float* __restrict__ b, float* __restrict__ ea)
{
    size_t e = (size_t)blockIdx.x * 256 + threadIdx.x;
    if (e >= NE) return;
    float o[HD];
    #pragma unroll
    for (int f = 0; f < HD; f++) o[f] = b[f];
    const float4* ar = (const float4*)(attr + e * ED);
    #pragma unroll
    for (int k4 = 0; k4 < ED / 4; k4++)
        gemm4(o, ar[k4], W + (k4 * 4) * HD);
    float4* er = (float4*)(ea + e * HD);
    #pragma unroll
    for (int f4 = 0; f4 < 16; f4++)
        er[f4] = make_float4(o[4*f4], o[4*f4+1], o[4*f4+2], o[4*f4+3]);
}

// ---------------- K3 (MFMA, zero LDS): msg = relu(h[src] + ea@W + b); atomic agg
__global__ __launch_bounds__(256) void k_gine_msg_mfma(
    const float* __restrict__ ea, const float* __restrict__ h,
    const int* __restrict__ src, const int* __restrict__ dst,
    const u16* __restrict__ wt, const float* __restrict__ b,
    float* __restrict__ agg)
{
    const int lane = threadIdx.x & 63, wv = threadIdx.x >> 6;
    const size_t e0 = ((size_t)blockIdx.x * 4 + wv) * 16;
    const int c = lane & 15, g = lane >> 4;
    const size_t erow = (e0 + c) * HD;

    f32x4 acc[4];
    #pragma unroll
    for (int tt = 0; tt < 4; tt++) {
        float bv = b[tt * 16 + c];
        acc[tt] = (f32x4){bv, bv, bv, bv};
    }
    #pragma unroll
    for (int k0 = 0; k0 < 64; k0 += 32) {
        bf16x8 af = pack8(ea + erow + k0 + 8 * g);     // A[row=c][k0+8g..+7]
        #pragma unroll
        for (int tt = 0; tt < 4; tt++) {
            bf16x8 bf = *(const bf16x8*)&wt[(tt * 16 + c) * HD + k0 + 8 * g];
            acc[tt] = __builtin_amdgcn_mfma_f32_16x16x32_bf16(af, bf, acc[tt], 0, 0, 0);
        }
    }
    int sv[4], dv[4];
    #pragma unroll
    for (int r = 0; r < 4; r++) { sv[r] = src[e0 + 4*g + r]; dv[r] = dst[e0 + 4*g + r]; }
    #pragma unroll
    for (int tt = 0; tt < 4; tt++)
        #pragma unroll
        for (int r = 0; r < 4; r++) {
            float m = acc[tt][r] + h[(size_t)sv[r] * HD + tt * 16 + c];
            m = fmaxf(m, 0.f);
            unsafeAtomicAdd(&agg[(size_t)dv[r] * HD + tt * 16 + c], m);
        }
}

// ---------------- K4: out2 = mlp2(relu(mlp1(h+agg)))  (thread per node)
__global__ __launch_bounds__(256) void k_node_mlp(
    const float* __restrict__ h, const float* __restrict__ agg,
    const float* __restrict__ W1, const float* __restrict__ b1,
    const float* __restrict__ W2, const float* __restrict__ b2,
    float* __restrict__ out2)
{
    int n = blockIdx.x * 256 + threadIdx.x;
    if (n >= NN) return;
    float o[HD];
    #pragma unroll
    for (int f = 0; f < HD; f++) o[f] = b1[f];
    const float4* hr = (const float4*)(h + (size_t)n * HD);
    const float4* ar = (const float4*)(agg + (size_t)n * HD);
    #pragma unroll 4
    for (int k4 = 0; k4 < 16; k4++) {
        float4 t1 = hr[k4], t2 = ar[k4];
        float4 t = make_float4(t1.x + t2.x, t1.y + t2.y, t1.z + t2.z, t1.w + t2.w);
        gemm4(o, t, W1 + (k4 * 4) * HD);
    }
    #pragma unroll
    for (int k = 0; k < HD; k++) o[k] = fmaxf(o[k], 0.f);
    #pragma unroll
    for (int c = 0; c < 4; c++) {
        float p[16];
        #pragma unroll
        for (int j = 0; j < 16; j++) p[j] = b2[c * 16 + j];
        for (int k = 0; k < HD; k++) {
            const float* Wr = W2 + k * HD + c * 16;
            #pragma unroll
            for (int j = 0; j < 16; j++) p[j] = fmaf(o[k], Wr[j], p[j]);
        }
        float4* orow = (float4*)(out2 + (size_t)n * HD + c * 16);
        #pragma unroll
        for (int q = 0; q < 4; q++)
            orow[q] = make_float4(p[4*q], p[4*q+1], p[4*q+2], p[4*q+3]);
    }
}

// ---------------- K4b: BN stats reduction (lane = feature, coalesced rows)
__global__ __launch_bounds__(256) void k_bnstats(
    const float* __restrict__ out2, float* __restrict__ bnst)
{
    int f = threadIdx.x & 63;
    int row0 = blockIdx.x * 4 + (threadIdx.x >> 6);
    float s = 0.f, q = 0.f;
    for (int r = row0; r < NN; r += gridDim.x * 4) {
        float v = out2[(size_t)r * HD + f];
        s += v; q += v * v;
    }
    unsafeAtomicAdd(&bnst[f], s);
    unsafeAtomicAdd(&bnst[HD + f], q);
}

// ---------------- K5: BN + h = (h + relu(out2*sc+sh)) * 0.5 ; also bf16 h copy
__global__ __launch_bounds__(256) void k_bn_h(
    const float* __restrict__ out2, const float* __restrict__ bnst,
    const float* __restrict__ gamma, const float* __restrict__ beta,
    float* __restrict__ h, u16* __restrict__ hbf, float* __restrict__ hout, int last)
{
    size_t idx = (size_t)blockIdx.x * 256 + threadIdx.x;
    if (idx >= (size_t)NN * HD) return;
    int f = (int)(idx & 63);
    float mu  = bnst[f] * (1.f / NN);
    float var = bnst[HD + f] * (1.f / NN) - mu * mu;
    float sc  = gamma[f] * rsqrtf(var + BN_EPS);
    float sh  = beta[f] - mu * sc;
    float o   = fmaxf(fmaf(out2[idx], sc, sh), 0.f);
    float hn  = (h[idx] + o) * 0.5f;
    h[idx] = hn;
    hbf[idx] = f2b(hn);
    if (last) hout[idx] = hn;
}

// ---------------- K6 (MFMA): ea += 0.5*mlp2(relu(mlp1([h_s|h_d|ea])))
// A-fragments direct from global (hbf bf16 / ea f32-packed); only sO in LDS
__global__ __launch_bounds__(256) void k_edge_upd_mfma(
    const u16* __restrict__ hbf, float* __restrict__ ea,
    const int* __restrict__ src, const int* __restrict__ dst,
    const u16* __restrict__ w1t, const float* __restrict__ b1,
    const u16* __restrict__ w2t, const float* __restrict__ b2)
{
    __shared__ u16 sO[4][16 * 72];   // 9.2 KB: inter-layer transpose only
    const int lane = threadIdx.x & 63, wv = threadIdx.x >> 6;
    const size_t e0 = ((size_t)blockIdx.x * 4 + wv) * 16;
    u16* sOw = sO[wv];
    const int c = lane & 15, g = lane >> 4;
    const int sv = src[e0 + c], dv = dst[e0 + c];   // A-row c's edge endpoints
    const size_t erow = (e0 + c) * HD;

    // ---- layer 1: O = relu(A @ W1 + b1), A = [h_src | h_dst | ea] ----
    f32x4 acc[4];
    #pragma unroll
    for (int tt = 0; tt < 4; tt++) {
        float bv = b1[tt * 16 + c];
        acc[tt] = (f32x4){bv, bv, bv, bv};
    }
    #pragma unroll
    for (int k0 = 0; k0 < 64; k0 += 32) {           // h_src section k=0..63
        bf16x8 af = *(const bf16x8*)&hbf[(size_t)sv * HD + k0 + 8 * g];
        #pragma unroll
        for (int tt = 0; tt < 4; tt++) {
            bf16x8 bf = *(const bf16x8*)&w1t[(tt * 16 + c) * 192 + k0 + 8 * g];
            acc[tt] = __builtin_amdgcn_mfma_f32_16x16x32_bf16(af, bf, acc[tt], 0, 0, 0);
        }
    }
    #pragma unroll
    for (int k0 = 0; k0 < 64; k0 += 32) {           // h_dst section k=64..127
        bf16x8 af = *(const bf16x8*)&hbf[(size_t)dv * HD + k0 + 8 * g];
        #pragma unroll
        for (int tt = 0; tt < 4; tt++) {
            bf16x8 bf = *(const bf16x8*)&w1t[(tt * 16 + c) * 192 + 64 + k0 + 8 * g];
            acc[tt] = __builtin_amdgcn_mfma_f32_16x16x32_bf16(af, bf, acc[tt], 0, 0, 0);
        }
    }
    #pragma unroll
    for (int k0 = 0; k0 < 64; k0 += 32) {           // ea section k=128..191
        bf16x8 af = pack8(ea + erow + k0 + 8 * g);
        #pragma unroll
        for (int tt = 0; tt < 4; tt++) {
            bf16x8 bf = *(const bf16x8*)&w1t[(tt * 16 + c) * 192 + 128 + k0 + 8 * g];
            acc[tt] = __builtin_amdgcn_mfma_f32_16x16x32_bf16(af, bf, acc[tt], 0, 0, 0);
        }
    }
    #pragma unroll
    for (int tt = 0; tt < 4; tt++)
        #pragma unroll
        for (int r = 0; r < 4; r++)
            sOw[(4 * g + r) * 72 + tt * 16 + c] = f2b(fmaxf(acc[tt][r], 0.f));
    WAVE_SYNC();

    // ---- layer 2: H = O @ W2 + b2 ----
    f32x4 acc2[4];
    #pragma unroll
    for (int tt = 0; tt < 4; tt++) {
        float bv = b2[tt * 16 + c];
        acc2[tt] = (f32x4){bv, bv, bv, bv};
    }
    #pragma unroll
    for (int k0 = 0; k0 < 64; k0 += 32) {
        bf16x8 af = *(const bf16x8*)&sOw[c * 72 + k0 + 8 * g];
        #pragma unroll
        for (int tt = 0; tt < 4; tt++) {
            bf16x8 bf = *(const bf16x8*)&w2t[(tt * 16 + c) * HD + k0 + 8 * g];
            acc2[tt] = __builtin_amdgcn_mfma_f32_16x16x32_bf16(af, bf, acc2[tt], 0, 0, 0);
        }
    }
    // ---- epilogue: ea += 0.5 * H  (f32 RMW, 64B-granule per 16 lanes) ----
    #pragma unroll
    for (int tt = 0; tt < 4; tt++)
        #pragma unroll
        for (int r = 0; r < 4; r++) {
            size_t a = (e0 + 4 * g + r) * HD + tt * 16 + c;
            ea[a] += 0.5f * acc2[tt][r];
        }
}

extern "C" void kernel_launch(void* const* d_in, const int* in_sizes, int n_in,
                              void* d_out, int out_size, void* d_ws, size_t ws_size,
                              hipStream_t stream)
{
    const float* x        = (const float*)d_in[0];
    const int*   ei       = (const int*)d_in[1];
    const float* eattr    = (const float*)d_in[2];
    const float* node_W   = (const float*)d_in[3];
    const float* node_b   = (const float*)d_in[4];
    const float* edge_W   = (const float*)d_in[5];
    const float* edge_b   = (const float*)d_in[6];
    const float* elin_W   = (const float*)d_in[7];
    const float* elin_b   = (const float*)d_in[8];
    const float* mlp1_W   = (const float*)d_in[9];
    const float* mlp1_b   = (const float*)d_in[10];
    const float* mlp2_W   = (const float*)d_in[11];
    const float* mlp2_b   = (const float*)d_in[12];
    const float* emlp1_W  = (const float*)d_in[13];
    const float* emlp1_b  = (const float*)d_in[14];
    const float* emlp2_W  = (const float*)d_in[15];
    const float* emlp2_b  = (const float*)d_in[16];
    const float* bn_gamma = (const float*)d_in[17];
    const float* bn_beta  = (const float*)d_in[18];

    // OUTPUT IS FLOAT32: h at [0, 3.2M), ea at [3.2M, 67.2M)
    float* hout = (float*)d_out;
    float* ea   = hout + (size_t)NN * HD;

    const int* src = ei;          // edge_index row-major (2, NE)
    const int* dst = ei + NE;

    float* hbuf = (float*)d_ws;
    float* agg  = hbuf + (size_t)NN * HD;
    float* out2 = agg + (size_t)NN * HD;
    float* bnst = out2 + (size_t)NN * HD;
    u16*   w1t  = (u16*)(bnst + 128);          // [2][64][192] bf16
    u16*   w2t  = w1t + 2 * 192 * HD;          // [2][64][64]  bf16
    u16*   welt = w2t + 2 * HD * HD;           // [2][64][64]  bf16 (elin)
    u16*   hbf  = welt + 2 * HD * HD;          // [NN][64] bf16
    size_t base_need = ((size_t)NN * HD * 3 + 128) * sizeof(float)
                     + (2 * 192 * HD + 4 * HD * HD + (size_t)NN * HD) * sizeof(u16);

    // ---- host-side sanity sentinels (decodable through absmax) ----
    static const int exp_sizes[19] = {
        1600000, 2000000, 16000000, 2048, 64, 1024, 64,
        8192, 128, 8192, 128, 8192, 128, 24576, 128, 8192, 128, 128, 128};
    float sentinel = 0.f;
    if (n_in != 19) sentinel = 6000.f;
    else {
        for (int i = 0; i < 19; i++)
            if (in_sizes[i] != exp_sizes[i]) { sentinel = 2000.f + 32.f * i; break; }
    }
    if (sentinel == 0.f && ws_size < base_need) sentinel = 7000.f;
    if (sentinel != 0.f) {
        k_fill<<<dim3((unsigned)(((size_t)NN * HD + 255) / 256)), dim3(256), 0, stream>>>(
            hout, sentinel, (size_t)NN * HD);
        k_fill<<<dim3((unsigned)(((size_t)NE * HD + 255) / 256)), dim3(256), 0, stream>>>(
            ea, 0.f, (size_t)NE * HD);
        return;
    }

    dim3 b256(256);
    const unsigned EG = (NE + 255) / 256;            // 3907
    const unsigned WG = NE / 64;                     // 15625 (4 wave-tiles/block)
    k_prep_w1<<<dim3((2 * 192 * HD + 255) / 256), b256, 0, stream>>>(emlp1_W, w1t);
    k_prep_w64<<<dim3((2 * HD * HD + 255) / 256), b256, 0, stream>>>(emlp2_W, w2t);
    k_prep_w64<<<dim3((2 * HD * HD + 255) / 256), b256, 0, stream>>>(elin_W, welt);
    k_node_proj<<<dim3((NN + 3) / 4), b256, 0, stream>>>(x, node_W, node_b, hbuf);
    k_edge_proj<<<dim3(EG), b256, 0, stream>>>(eattr, edge_W, edge_b, ea);
    for (int i = 0; i < 2; i++) {
        hipMemsetAsync(agg, 0, (size_t)NN * HD * sizeof(float), stream);
        hipMemsetAsync(bnst, 0, 128 * sizeof(float), stream);
        k_gine_msg_mfma<<<dim3(WG), b256, 0, stream>>>(
            ea, hbuf, src, dst, welt + (size_t)i * HD * HD, elin_b + i * HD, agg);
        k_node_mlp<<<dim3((NN + 255) / 256), b256, 0, stream>>>(
            hbuf, agg, mlp1_W + i * HD * HD, mlp1_b + i * HD,
            mlp2_W + i * HD * HD, mlp2_b + i * HD, out2);
        k_bnstats<<<dim3(256), b256, 0, stream>>>(out2, bnst);
        k_bn_h<<<dim3((NN * HD + 255) / 256), b256, 0, stream>>>(
            out2, bnst, bn_gamma + i * HD, bn_beta + i * HD, hbuf, hbf, hout, i == 1);
        k_edge_upd_mfma<<<dim3(WG), b256, 0, stream>>>(
            hbf, ea, src, dst,
            w1t + (size_t)i * 192 * HD, emlp1_b + i * HD,
            w2t + (size_t)i * HD * HD, emlp2_b + i * HD);
    }
}

// Round 14
// 1310.782 us; speedup vs baseline: 1.1202x; 1.1202x over previous
//
#include <hip/hip_runtime.h>
#include <hip/hip_bf16.h>

#define NN 50000
#define NE 1000000
#define NF 32
#define ED 16
#define HD 64
#define BN_EPS 1e-5f

typedef unsigned short u16;
typedef __attribute__((ext_vector_type(8))) short bf16x8;
typedef __attribute__((ext_vector_type(4))) float f32x4;

// wave-level LDS fence: ds_writes complete + no compiler reordering (rule #18)
#define WAVE_SYNC() do { \
    asm volatile("s_waitcnt lgkmcnt(0)" ::: "memory"); \
    __builtin_amdgcn_sched_barrier(0); \
} while (0)

__device__ __forceinline__ u16 f2b(float x)
{
    __hip_bfloat16 b = __float2bfloat16(x);
    u16 u; __builtin_memcpy(&u, &b, 2); return u;
}

// pack 8 consecutive f32 -> bf16x8 fragment (in registers)
__device__ __forceinline__ bf16x8 pack8(const float* __restrict__ p)
{
    float4 v0 = ((const float4*)p)[0];
    float4 v1 = ((const float4*)p)[1];
    union { uint u[4]; bf16x8 v; } r;
    r.u[0] = (uint)f2b(v0.x) | ((uint)f2b(v0.y) << 16);
    r.u[1] = (uint)f2b(v0.z) | ((uint)f2b(v0.w) << 16);
    r.u[2] = (uint)f2b(v1.x) | ((uint)f2b(v1.y) << 16);
    r.u[3] = (uint)f2b(v1.z) | ((uint)f2b(v1.w) << 16);
    return r.v;
}

// ---------------- diag: fill an f32 region with a sentinel constant
__global__ __launch_bounds__(256) void k_fill(float* p, float v, size_t n)
{
    size_t i = (size_t)blockIdx.x * 256 + threadIdx.x;
    if (i < n) p[i] = v;
}

// rank-4 update: o += t * W[0:4][:]  (weights wave-uniform)
__device__ __forceinline__ void gemm4(float (&o)[HD], float4 t, const float* __restrict__ Wr)
{
    #pragma unroll
    for (int f = 0; f < HD; f++) o[f] = fmaf(t.x, Wr[f], o[f]);
    #pragma unroll
    for (int f = 0; f < HD; f++) o[f] = fmaf(t.y, Wr[HD + f], o[f]);
    #pragma unroll
    for (int f = 0; f < HD; f++) o[f] = fmaf(t.z, Wr[2 * HD + f], o[f]);
    #pragma unroll
    for (int f = 0; f < HD; f++) o[f] = fmaf(t.w, Wr[3 * HD + f], o[f]);
}

// ---------------- prep: W1[l][k][f] (f32) -> w1t[l][f][k] (bf16), k=0..191
__global__ __launch_bounds__(256) void k_prep_w1(const float* __restrict__ W, u16* __restrict__ out)
{
    int idx = blockIdx.x * 256 + threadIdx.x;
    if (idx >= 2 * 192 * HD) return;
    int l = idx / (192 * HD), r = idx % (192 * HD), k = r / HD, f = r % HD;
    out[l * 192 * HD + f * 192 + k] = f2b(W[idx]);
}
// ---------------- prep: 2 layers of [64][64] (k,f) -> (f,k) bf16
__global__ __launch_bounds__(256) void k_prep_w64(const float* __restrict__ W, u16* __restrict__ out)
{
    int idx = blockIdx.x * 256 + threadIdx.x;
    if (idx >= 2 * HD * HD) return;
    int l = idx / (HD * HD), r = idx % (HD * HD), k = r / HD, f = r % HD;
    out[l * HD * HD + f * HD + k] = f2b(W[idx]);
}

// ---------------- K1: h = x @ node_W + node_b  (wave per node, K=32 via shfl)
__global__ __launch_bounds__(256) void k_node_proj(
    const float* __restrict__ x, const float* __restrict__ W,
    const float* __restrict__ b, float* __restrict__ h)
{
    __shared__ float sW[NF * HD];   // 8 KB
    for (int t = threadIdx.x; t < NF * HD; t += 256) sW[t] = W[t];
    __syncthreads();
    int lane = threadIdx.x & 63, wv = threadIdx.x >> 6;
    int n = blockIdx.x * 4 + wv;
    if (n >= NN) return;
    float a = (lane < NF) ? x[(size_t)n * NF + lane] : 0.f;
    float acc = b[lane];
    #pragma unroll
    for (int k = 0; k < NF; k++) acc = fmaf(__shfl(a, k), sW[k * HD + lane], acc);
    h[(size_t)n * HD + lane] = acc;
}

// ---------------- K2: ea = edge_attr @ edge_W + edge_b  (thread per edge)
__global__ __launch_bounds__(256) void k_edge_proj(
    const float* __restrict__ attr, const float* __restrict__ W,
    const float* __restrict__ b, float* __restrict__ ea)
{
    size_t e = (size_t)blockIdx.x * 256 + threadIdx.x;
    if (e >= NE) return;
    float o[HD];
    #pragma unroll
    for (int f = 0; f < HD; f++) o[f] = b[f];
    const float4* ar = (const float4*)(attr + e * ED);
    #pragma unroll
    for (int k4 = 0; k4 < ED / 4; k4++)
        gemm4(o, ar[k4], W + (k4 * 4) * HD);
    float4* er = (float4*)(ea + e * HD);
    #pragma unroll
    for (int f4 = 0; f4 < 16; f4++)
        er[f4] = make_float4(o[4*f4], o[4*f4+1], o[4*f4+2], o[4*f4+3]);
}

// ---------------- K3 (MFMA, zero LDS, 32 edges/wave): msg -> atomic agg[dst]
__global__ __launch_bounds__(256) void k_gine_msg_mfma(
    const float* __restrict__ ea, const float* __restrict__ h,
    const int* __restrict__ src, const int* __restrict__ dst,
    const u16* __restrict__ wt, const float* __restrict__ b,
    float* __restrict__ agg)
{
    const int lane = threadIdx.x & 63, wv = threadIdx.x >> 6;
    const size_t base = ((size_t)blockIdx.x * 4 + wv) * 32;
    if (base >= NE) return;
    const int c = lane & 15, g = lane >> 4;

    // load all A-fragments up front (4 x 16B-equivalent, in-register pack)
    bf16x8 ae[2][2];
    #pragma unroll
    for (int s = 0; s < 2; s++) {
        const float* ep = ea + (base + 16 * s + c) * HD + 8 * g;
        ae[s][0] = pack8(ep);
        ae[s][1] = pack8(ep + 32);
    }
    // epilogue indices early (8 scattered int loads in flight)
    int sv[2][4], dv[2][4];
    #pragma unroll
    for (int s = 0; s < 2; s++)
        #pragma unroll
        for (int r = 0; r < 4; r++) {
            sv[s][r] = src[base + 16 * s + 4 * g + r];
            dv[s][r] = dst[base + 16 * s + 4 * g + r];
        }

    f32x4 acc[2][4];
    #pragma unroll
    for (int s = 0; s < 2; s++)
        #pragma unroll
        for (int tt = 0; tt < 4; tt++) {
            float bv = b[tt * 16 + c];
            acc[s][tt] = (f32x4){bv, bv, bv, bv};
        }
    #pragma unroll
    for (int ki = 0; ki < 2; ki++)
        #pragma unroll
        for (int tt = 0; tt < 4; tt++) {
            bf16x8 bw = *(const bf16x8*)&wt[(tt * 16 + c) * HD + ki * 32 + 8 * g];
            acc[0][tt] = __builtin_amdgcn_mfma_f32_16x16x32_bf16(ae[0][ki], bw, acc[0][tt], 0, 0, 0);
            acc[1][tt] = __builtin_amdgcn_mfma_f32_16x16x32_bf16(ae[1][ki], bw, acc[1][tt], 0, 0, 0);
        }
    #pragma unroll
    for (int s = 0; s < 2; s++)
        #pragma unroll
        for (int tt = 0; tt < 4; tt++)
            #pragma unroll
            for (int r = 0; r < 4; r++) {
                float m = acc[s][tt][r] + h[(size_t)sv[s][r] * HD + tt * 16 + c];
                m = fmaxf(m, 0.f);
                unsafeAtomicAdd(&agg[(size_t)dv[s][r] * HD + tt * 16 + c], m);
            }
}

// ---------------- K4: out2 = mlp2(relu(mlp1(h+agg)))  (thread per node)
__global__ __launch_bounds__(256) void k_node_mlp(
    const float* __restrict__ h, const float* __restrict__ agg,
    const float* __restrict__ W1, const float* __restrict__ b1,
    const float* __restrict__ W2, const float* __restrict__ b2,
    float* __restrict__ out2)
{
    int n = blockIdx.x * 256 + threadIdx.x;
    if (n >= NN) return;
    float o[HD];
    #pragma unroll
    for (int f = 0; f < HD; f++) o[f] = b1[f];
    const float4* hr = (const float4*)(h + (size_t)n * HD);
    const float4* ar = (const float4*)(agg + (size_t)n * HD);
    #pragma unroll 4
    for (int k4 = 0; k4 < 16; k4++) {
        float4 t1 = hr[k4], t2 = ar[k4];
        float4 t = make_float4(t1.x + t2.x, t1.y + t2.y, t1.z + t2.z, t1.w + t2.w);
        gemm4(o, t, W1 + (k4 * 4) * HD);
    }
    #pragma unroll
    for (int k = 0; k < HD; k++) o[k] = fmaxf(o[k], 0.f);
    #pragma unroll
    for (int c = 0; c < 4; c++) {
        float p[16];
        #pragma unroll
        for (int j = 0; j < 16; j++) p[j] = b2[c * 16 + j];
        for (int k = 0; k < HD; k++) {
            const float* Wr = W2 + k * HD + c * 16;
            #pragma unroll
            for (int j = 0; j < 16; j++) p[j] = fmaf(o[k], Wr[j], p[j]);
        }
        float4* orow = (float4*)(out2 + (size_t)n * HD + c * 16);
        #pragma unroll
        for (int q = 0; q < 4; q++)
            orow[q] = make_float4(p[4*q], p[4*q+1], p[4*q+2], p[4*q+3]);
    }
}

// ---------------- K4b: BN stats reduction (lane = feature, coalesced rows)
__global__ __launch_bounds__(256) void k_bnstats(
    const float* __restrict__ out2, float* __restrict__ bnst)
{
    int f = threadIdx.x & 63;
    int row0 = blockIdx.x * 4 + (threadIdx.x >> 6);
    float s = 0.f, q = 0.f;
    for (int r = row0; r < NN; r += gridDim.x * 4) {
        float v = out2[(size_t)r * HD + f];
        s += v; q += v * v;
    }
    unsafeAtomicAdd(&bnst[f], s);
    unsafeAtomicAdd(&bnst[HD + f], q);
}

// ---------------- K5: BN + h = (h + relu(out2*sc+sh)) * 0.5 ; also bf16 h copy
__global__ __launch_bounds__(256) void k_bn_h(
    const float* __restrict__ out2, const float* __restrict__ bnst,
    const float* __restrict__ gamma, const float* __restrict__ beta,
    float* __restrict__ h, u16* __restrict__ hbf, float* __restrict__ hout, int last)
{
    size_t idx = (size_t)blockIdx.x * 256 + threadIdx.x;
    if (idx >= (size_t)NN * HD) return;
    int f = (int)(idx & 63);
    float mu  = bnst[f] * (1.f / NN);
    float var = bnst[HD + f] * (1.f / NN) - mu * mu;
    float sc  = gamma[f] * rsqrtf(var + BN_EPS);
    float sh  = beta[f] - mu * sc;
    float o   = fmaxf(fmaf(out2[idx], sc, sh), 0.f);
    float hn  = (h[idx] + o) * 0.5f;
    h[idx] = hn;
    hbf[idx] = f2b(hn);
    if (last) hout[idx] = hn;
}

// ---------------- K6 (MFMA, 32 edges/wave): ea += 0.5*mlp2(relu(mlp1([h_s|h_d|ea])))
// A-fragments direct-to-register; weight fragments loaded once, used for both
// sub-tiles; only sO (inter-layer transpose) in LDS.
__global__ __launch_bounds__(256) void k_edge_upd_mfma(
    const u16* __restrict__ hbf, float* __restrict__ ea,
    const int* __restrict__ src, const int* __restrict__ dst,
    const u16* __restrict__ w1t, const float* __restrict__ b1,
    const u16* __restrict__ w2t, const float* __restrict__ b2)
{
    __shared__ u16 sO[4][32 * 72];   // 18 KB
    const int lane = threadIdx.x & 63, wv = threadIdx.x >> 6;
    const size_t base = ((size_t)blockIdx.x * 4 + wv) * 32;
    if (base >= NE) return;
    u16* sOw = sO[wv];
    const int c = lane & 15, g = lane >> 4;

    int sv[2], dv[2];
    #pragma unroll
    for (int s = 0; s < 2; s++) {
        sv[s] = src[base + 16 * s + c];
        dv[s] = dst[base + 16 * s + c];
    }

    // all 12 A-fragments up front: A[sec][subtile][kchunk]
    bf16x8 A[3][2][2];
    #pragma unroll
    for (int s = 0; s < 2; s++) {
        const u16* hs = &hbf[(size_t)sv[s] * HD + 8 * g];
        A[0][s][0] = *(const bf16x8*)hs;
        A[0][s][1] = *(const bf16x8*)(hs + 32);
        const u16* hd = &hbf[(size_t)dv[s] * HD + 8 * g];
        A[1][s][0] = *(const bf16x8*)hd;
        A[1][s][1] = *(const bf16x8*)(hd + 32);
        const float* ep = ea + (base + 16 * s + c) * HD + 8 * g;
        A[2][s][0] = pack8(ep);
        A[2][s][1] = pack8(ep + 32);
    }

    // ---- layer 1: O = relu(A @ W1 + b1) ----
    f32x4 acc[2][4];
    #pragma unroll
    for (int s = 0; s < 2; s++)
        #pragma unroll
        for (int tt = 0; tt < 4; tt++) {
            float bv = b1[tt * 16 + c];
            acc[s][tt] = (f32x4){bv, bv, bv, bv};
        }
    #pragma unroll
    for (int sec = 0; sec < 3; sec++)
        #pragma unroll
        for (int ki = 0; ki < 2; ki++)
            #pragma unroll
            for (int tt = 0; tt < 4; tt++) {
                bf16x8 bw = *(const bf16x8*)&w1t[(tt * 16 + c) * 192 + sec * 64 + ki * 32 + 8 * g];
                acc[0][tt] = __builtin_amdgcn_mfma_f32_16x16x32_bf16(A[sec][0][ki], bw, acc[0][tt], 0, 0, 0);
                acc[1][tt] = __builtin_amdgcn_mfma_f32_16x16x32_bf16(A[sec][1][ki], bw, acc[1][tt], 0, 0, 0);
            }
    #pragma unroll
    for (int s = 0; s < 2; s++)
        #pragma unroll
        for (int tt = 0; tt < 4; tt++)
            #pragma unroll
            for (int r = 0; r < 4; r++)
                sOw[(16 * s + 4 * g + r) * 72 + tt * 16 + c] = f2b(fmaxf(acc[s][tt][r], 0.f));
    WAVE_SYNC();

    // ---- layer 2: H = O @ W2 + b2 ----
    bf16x8 A2[2][2];
    #pragma unroll
    for (int s = 0; s < 2; s++) {
        A2[s][0] = *(const bf16x8*)&sOw[(16 * s + c) * 72 + 8 * g];
        A2[s][1] = *(const bf16x8*)&sOw[(16 * s + c) * 72 + 32 + 8 * g];
    }
    WAVE_SYNC();
    f32x4 acc2[2][4];
    #pragma unroll
    for (int s = 0; s < 2; s++)
        #pragma unroll
        for (int tt = 0; tt < 4; tt++) {
            float bv = b2[tt * 16 + c];
            acc2[s][tt] = (f32x4){bv, bv, bv, bv};
        }
    #pragma unroll
    for (int ki = 0; ki < 2; ki++)
        #pragma unroll
        for (int tt = 0; tt < 4; tt++) {
            bf16x8 bw = *(const bf16x8*)&w2t[(tt * 16 + c) * HD + ki * 32 + 8 * g];
            acc2[0][tt] = __builtin_amdgcn_mfma_f32_16x16x32_bf16(A2[0][ki], bw, acc2[0][tt], 0, 0, 0);
            acc2[1][tt] = __builtin_amdgcn_mfma_f32_16x16x32_bf16(A2[1][ki], bw, acc2[1][tt], 0, 0, 0);
        }
    // ---- epilogue: ea += 0.5 * H  (f32 RMW, 64B-granule per 16 lanes) ----
    #pragma unroll
    for (int s = 0; s < 2; s++)
        #pragma unroll
        for (int tt = 0; tt < 4; tt++)
            #pragma unroll
            for (int r = 0; r < 4; r++) {
                size_t a = (base + 16 * s + 4 * g + r) * HD + tt * 16 + c;
                ea[a] += 0.5f * acc2[s][tt][r];
            }
}

extern "C" void kernel_launch(void* const* d_in, const int* in_sizes, int n_in,
                              void* d_out, int out_size, void* d_ws, size_t ws_size,
                              hipStream_t stream)
{
    const float* x        = (const float*)d_in[0];
    const int*   ei       = (const int*)d_in[1];
    const float* eattr    = (const float*)d_in[2];
    const float* node_W   = (const float*)d_in[3];
    const float* node_b   = (const float*)d_in[4];
    const float* edge_W   = (const float*)d_in[5];
    const float* edge_b   = (const float*)d_in[6];
    const float* elin_W   = (const float*)d_in[7];
    const float* elin_b   = (const float*)d_in[8];
    const float* mlp1_W   = (const float*)d_in[9];
    const float* mlp1_b   = (const float*)d_in[10];
    const float* mlp2_W   = (const float*)d_in[11];
    const float* mlp2_b   = (const float*)d_in[12];
    const float* emlp1_W  = (const float*)d_in[13];
    const float* emlp1_b  = (const float*)d_in[14];
    const float* emlp2_W  = (const float*)d_in[15];
    const float* emlp2_b  = (const float*)d_in[16];
    const float* bn_gamma = (const float*)d_in[17];
    const float* bn_beta  = (const float*)d_in[18];

    // OUTPUT IS FLOAT32: h at [0, 3.2M), ea at [3.2M, 67.2M)
    float* hout = (float*)d_out;
    float* ea   = hout + (size_t)NN * HD;

    const int* src = ei;          // edge_index row-major (2, NE)
    const int* dst = ei + NE;

    float* hbuf = (float*)d_ws;
    float* agg  = hbuf + (size_t)NN * HD;
    float* out2 = agg + (size_t)NN * HD;
    float* bnst = out2 + (size_t)NN * HD;
    u16*   w1t  = (u16*)(bnst + 128);          // [2][64][192] bf16
    u16*   w2t  = w1t + 2 * 192 * HD;          // [2][64][64]  bf16
    u16*   welt = w2t + 2 * HD * HD;           // [2][64][64]  bf16 (elin)
    u16*   hbf  = welt + 2 * HD * HD;          // [NN][64] bf16
    size_t base_need = ((size_t)NN * HD * 3 + 128) * sizeof(float)
                     + (2 * 192 * HD + 4 * HD * HD + (size_t)NN * HD) * sizeof(u16);

    // ---- host-side sanity sentinels (decodable through absmax) ----
    static const int exp_sizes[19] = {
        1600000, 2000000, 16000000, 2048, 64, 1024, 64,
        8192, 128, 8192, 128, 8192, 128, 24576, 128, 8192, 128, 128, 128};
    float sentinel = 0.f;
    if (n_in != 19) sentinel = 6000.f;
    else {
        for (int i = 0; i < 19; i++)
            if (in_sizes[i] != exp_sizes[i]) { sentinel = 2000.f + 32.f * i; break; }
    }
    if (sentinel == 0.f && ws_size < base_need) sentinel = 7000.f;
    if (sentinel != 0.f) {
        k_fill<<<dim3((unsigned)(((size_t)NN * HD + 255) / 256)), dim3(256), 0, stream>>>(
            hout, sentinel, (size_t)NN * HD);
        k_fill<<<dim3((unsigned)(((size_t)NE * HD + 255) / 256)), dim3(256), 0, stream>>>(
            ea, 0.f, (size_t)NE * HD);
        return;
    }

    dim3 b256(256);
    const unsigned EG  = (NE + 255) / 256;           // 3907
    const unsigned WG2 = (NE + 127) / 128;           // 7813 (4 waves x 32 edges)
    k_prep_w1<<<dim3((2 * 192 * HD + 255) / 256), b256, 0, stream>>>(emlp1_W, w1t);
    k_prep_w64<<<dim3((2 * HD * HD + 255) / 256), b256, 0, stream>>>(emlp2_W, w2t);
    k_prep_w64<<<dim3((2 * HD * HD + 255) / 256), b256, 0, stream>>>(elin_W, welt);
    k_node_proj<<<dim3((NN + 3) / 4), b256, 0, stream>>>(x, node_W, node_b, hbuf);
    k_edge_proj<<<dim3(EG), b256, 0, stream>>>(eattr, edge_W, edge_b, ea);
    for (int i = 0; i < 2; i++) {
        hipMemsetAsync(agg, 0, (size_t)NN * HD * sizeof(float), stream);
        hipMemsetAsync(bnst, 0, 128 * sizeof(float), stream);
        k_gine_msg_mfma<<<dim3(WG2), b256, 0, stream>>>(
            ea, hbuf, src, dst, welt + (size_t)i * HD * HD, elin_b + i * HD, agg);
        k_node_mlp<<<dim3((NN + 255) / 256), b256, 0, stream>>>(
            hbuf, agg, mlp1_W + i * HD * HD, mlp1_b + i * HD,
            mlp2_W + i * HD * HD, mlp2_b + i * HD, out2);
        k_bnstats<<<dim3(256), b256, 0, stream>>>(out2, bnst);
        k_bn_h<<<dim3((NN * HD + 255) / 256), b256, 0, stream>>>(
            out2, bnst, bn_gamma + i * HD, bn_beta + i * HD, hbuf, hbf, hout, i == 1);
        k_edge_upd_mfma<<<dim3(WG2), b256, 0, stream>>>(
            hbf, ea, src, dst,
            w1t + (size_t)i * 192 * HD, emlp1_b + i * HD,
            w2t + (size_t)i * HD * HD, emlp2_b + i * HD);
    }
}

// Round 18
// 1062.940 us; speedup vs baseline: 1.3814x; 1.2332x over previous
//
#include <hip/hip_runtime.h>
#include <hip/hip_bf16.h>

#define NN 50000
#define NE 1000000
#define NF 32
#define ED 16
#define HD 64
#define BN_EPS 1e-5f

typedef unsigned short u16;
typedef __attribute__((ext_vector_type(8))) short bf16x8;
typedef __attribute__((ext_vector_type(4))) float f32x4;

// wave-level LDS fence: ds ops complete + no compiler reordering (rule #18)
#define WAVE_SYNC() do { \
    asm volatile("s_waitcnt lgkmcnt(0)" ::: "memory"); \
    __builtin_amdgcn_sched_barrier(0); \
} while (0)

__device__ __forceinline__ u16 f2b(float x)
{
    __hip_bfloat16 b = __float2bfloat16(x);
    u16 u; __builtin_memcpy(&u, &b, 2); return u;
}
__device__ __forceinline__ float b2f(u16 u)
{
    uint v = (uint)u << 16; float f; __builtin_memcpy(&f, &v, 4); return f;
}

// ---------------- diag: fill an f32 region with a sentinel constant
__global__ __launch_bounds__(256) void k_fill(float* p, float v, size_t n)
{
    size_t i = (size_t)blockIdx.x * 256 + threadIdx.x;
    if (i < n) p[i] = v;
}

// rank-4 update: o += t * W[0:4][:]  (weights wave-uniform)
__device__ __forceinline__ void gemm4(float (&o)[HD], float4 t, const float* __restrict__ Wr)
{
    #pragma unroll
    for (int f = 0; f < HD; f++) o[f] = fmaf(t.x, Wr[f], o[f]);
    #pragma unroll
    for (int f = 0; f < HD; f++) o[f] = fmaf(t.y, Wr[HD + f], o[f]);
    #pragma unroll
    for (int f = 0; f < HD; f++) o[f] = fmaf(t.z, Wr[2 * HD + f], o[f]);
    #pragma unroll
    for (int f = 0; f < HD; f++) o[f] = fmaf(t.w, Wr[3 * HD + f], o[f]);
}

// ---------------- prep: W1[l][k][f] (f32) -> w1t[l][f][k] (bf16), k=0..191
__global__ __launch_bounds__(256) void k_prep_w1(const float* __restrict__ W, u16* __restrict__ out)
{
    int idx = blockIdx.x * 256 + threadIdx.x;
    if (idx >= 2 * 192 * HD) return;
    int l = idx / (192 * HD), r = idx % (192 * HD), k = r / HD, f = r % HD;
    out[l * 192 * HD + f * 192 + k] = f2b(W[idx]);
}
// ---------------- prep: 2 layers of [64][64] (k,f) -> (f,k) bf16
__global__ __launch_bounds__(256) void k_prep_w64(const float* __restrict__ W, u16* __restrict__ out)
{
    int idx = blockIdx.x * 256 + threadIdx.x;
    if (idx >= 2 * HD * HD) return;
    int l = idx / (HD * HD), r = idx % (HD * HD), k = r / HD, f = r % HD;
    out[l * HD * HD + f * HD + k] = f2b(W[idx]);
}

// ---------------- K1: h = x @ node_W + node_b  (wave per node, K=32 via shfl)
__global__ __launch_bounds__(256) void k_node_proj(
    const float* __restrict__ x, const float* __restrict__ W,
    const float* __restrict__ b, float* __restrict__ h)
{
    __shared__ float sW[NF * HD];   // 8 KB
    for (int t = threadIdx.x; t < NF * HD; t += 256) sW[t] = W[t];
    __syncthreads();
    int lane = threadIdx.x & 63, wv = threadIdx.x >> 6;
    int n = blockIdx.x * 4 + wv;
    if (n >= NN) return;
    float a = (lane < NF) ? x[(size_t)n * NF + lane] : 0.f;
    float acc = b[lane];
    #pragma unroll
    for (int k = 0; k < NF; k++) acc = fmaf(__shfl(a, k), sW[k * HD + lane], acc);
    h[(size_t)n * HD + lane] = acc;
}

// ---------------- K2: eab = bf16(edge_attr @ edge_W + edge_b)  (thread per edge)
__global__ __launch_bounds__(256) void k_edge_proj(
    const float* __restrict__ attr, const float* __restrict__ W,
    const float* __restrict__ b, u16* __restrict__ eab)
{
    size_t e = (size_t)blockIdx.x * 256 + threadIdx.x;
    if (e >= NE) return;
    float o[HD];
    #pragma unroll
    for (int f = 0; f < HD; f++) o[f] = b[f];
    const float4* ar = (const float4*)(attr + e * ED);
    #pragma unroll
    for (int k4 = 0; k4 < ED / 4; k4++)
        gemm4(o, ar[k4], W + (k4 * 4) * HD);
    uint* er = (uint*)(eab + e * HD);
    #pragma unroll
    for (int f2 = 0; f2 < 32; f2++)
        er[f2] = (uint)f2b(o[2 * f2]) | ((uint)f2b(o[2 * f2 + 1]) << 16);
}

// ---------------- K3 (MFMA, zero LDS, 32 edges/wave): msg -> atomic agg[dst]
__global__ __launch_bounds__(256) void k_gine_msg_mfma(
    const u16* __restrict__ eab, const float* __restrict__ h,
    const int* __restrict__ src, const int* __restrict__ dst,
    const u16* __restrict__ wt, const float* __restrict__ b,
    float* __restrict__ agg)
{
    const int lane = threadIdx.x & 63, wv = threadIdx.x >> 6;
    const size_t base = ((size_t)blockIdx.x * 4 + wv) * 32;
    if (base >= NE) return;
    const int c = lane & 15, g = lane >> 4;

    bf16x8 ae[2][2];
    #pragma unroll
    for (int s = 0; s < 2; s++) {
        const u16* ep = &eab[(base + 16 * s + c) * HD + 8 * g];
        ae[s][0] = *(const bf16x8*)ep;
        ae[s][1] = *(const bf16x8*)(ep + 32);
    }
    int sv[2][4], dv[2][4];
    #pragma unroll
    for (int s = 0; s < 2; s++)
        #pragma unroll
        for (int r = 0; r < 4; r++) {
            sv[s][r] = src[base + 16 * s + 4 * g + r];
            dv[s][r] = dst[base + 16 * s + 4 * g + r];
        }

    f32x4 acc[2][4];
    #pragma unroll
    for (int s = 0; s < 2; s++)
        #pragma unroll
        for (int tt = 0; tt < 4; tt++) {
            float bv = b[tt * 16 + c];
            acc[s][tt] = (f32x4){bv, bv, bv, bv};
        }
    #pragma unroll
    for (int ki = 0; ki < 2; ki++)
        #pragma unroll
        for (int tt = 0; tt < 4; tt++) {
            bf16x8 bw = *(const bf16x8*)&wt[(tt * 16 + c) * HD + ki * 32 + 8 * g];
            acc[0][tt] = __builtin_amdgcn_mfma_f32_16x16x32_bf16(ae[0][ki], bw, acc[0][tt], 0, 0, 0);
            acc[1][tt] = __builtin_amdgcn_mfma_f32_16x16x32_bf16(ae[1][ki], bw, acc[1][tt], 0, 0, 0);
        }
    #pragma unroll
    for (int s = 0; s < 2; s++)
        #pragma unroll
        for (int tt = 0; tt < 4; tt++)
            #pragma unroll
            for (int r = 0; r < 4; r++) {
                float m = acc[s][tt][r] + h[(size_t)sv[s][r] * HD + tt * 16 + c];
                m = fmaxf(m, 0.f);
                unsafeAtomicAdd(&agg[(size_t)dv[s][r] * HD + tt * 16 + c], m);
            }
}

// ---------------- K4: out2 = mlp2(relu(mlp1(h+agg)))  (thread per node)
__global__ __launch_bounds__(256) void k_node_mlp(
    const float* __restrict__ h, const float* __restrict__ agg,
    const float* __restrict__ W1, const float* __restrict__ b1,
    const float* __restrict__ W2, const float* __restrict__ b2,
    float* __restrict__ out2)
{
    int n = blockIdx.x * 256 + threadIdx.x;
    if (n >= NN) return;
    float o[HD];
    #pragma unroll
    for (int f = 0; f < HD; f++) o[f] = b1[f];
    const float4* hr = (const float4*)(h + (size_t)n * HD);
    const float4* ar = (const float4*)(agg + (size_t)n * HD);
    #pragma unroll 4
    for (int k4 = 0; k4 < 16; k4++) {
        float4 t1 = hr[k4], t2 = ar[k4];
        float4 t = make_float4(t1.x + t2.x, t1.y + t2.y, t1.z + t2.z, t1.w + t2.w);
        gemm4(o, t, W1 + (k4 * 4) * HD);
    }
    #pragma unroll
    for (int k = 0; k < HD; k++) o[k] = fmaxf(o[k], 0.f);
    #pragma unroll
    for (int c = 0; c < 4; c++) {
        float p[16];
        #pragma unroll
        for (int j = 0; j < 16; j++) p[j] = b2[c * 16 + j];
        for (int k = 0; k < HD; k++) {
            const float* Wr = W2 + k * HD + c * 16;
            #pragma unroll
            for (int j = 0; j < 16; j++) p[j] = fmaf(o[k], Wr[j], p[j]);
        }
        float4* orow = (float4*)(out2 + (size_t)n * HD + c * 16);
        #pragma unroll
        for (int q = 0; q < 4; q++)
            orow[q] = make_float4(p[4*q], p[4*q+1], p[4*q+2], p[4*q+3]);
    }
}

// ---------------- K4b: BN stats reduction (lane = feature, coalesced rows)
__global__ __launch_bounds__(256) void k_bnstats(
    const float* __restrict__ out2, float* __restrict__ bnst)
{
    int f = threadIdx.x & 63;
    int row0 = blockIdx.x * 4 + (threadIdx.x >> 6);
    float s = 0.f, q = 0.f;
    for (int r = row0; r < NN; r += gridDim.x * 4) {
        float v = out2[(size_t)r * HD + f];
        s += v; q += v * v;
    }
    unsafeAtomicAdd(&bnst[f], s);
    unsafeAtomicAdd(&bnst[HD + f], q);
}

// ---------------- K5: BN + h = (h + relu(out2*sc+sh)) * 0.5 ; also bf16 h copy
__global__ __launch_bounds__(256) void k_bn_h(
    const float* __restrict__ out2, const float* __restrict__ bnst,
    const float* __restrict__ gamma, const float* __restrict__ beta,
    float* __restrict__ h, u16* __restrict__ hbf, float* __restrict__ hout, int last)
{
    size_t idx = (size_t)blockIdx.x * 256 + threadIdx.x;
    if (idx >= (size_t)NN * HD) return;
    int f = (int)(idx & 63);
    float mu  = bnst[f] * (1.f / NN);
    float var = bnst[HD + f] * (1.f / NN) - mu * mu;
    float sc  = gamma[f] * rsqrtf(var + BN_EPS);
    float sh  = beta[f] - mu * sc;
    float o   = fmaxf(fmaf(out2[idx], sc, sh), 0.f);
    float hn  = (h[idx] + o) * 0.5f;
    h[idx] = hn;
    hbf[idx] = f2b(hn);
    if (last) hout[idx] = hn;
}

// shared core: layer-1 + layer-2 MFMA for the edge MLP (32 edges/wave)
// returns acc2 (update, D layout). A-fragments direct from global bf16.
__device__ __forceinline__ void edge_mlp_core(
    const u16* __restrict__ hbf, const u16* __restrict__ eab,
    const int* __restrict__ src, const int* __restrict__ dst,
    const u16* __restrict__ w1t, const float* __restrict__ b1,
    const u16* __restrict__ w2t, const float* __restrict__ b2,
    u16* sOw, size_t base, int c, int g, f32x4 (&acc2)[2][4])
{
    int sv[2], dv[2];
    #pragma unroll
    for (int s = 0; s < 2; s++) {
        sv[s] = src[base + 16 * s + c];
        dv[s] = dst[base + 16 * s + c];
    }
    bf16x8 A[3][2][2];
    #pragma unroll
    for (int s = 0; s < 2; s++) {
        const u16* hs = &hbf[(size_t)sv[s] * HD + 8 * g];
        A[0][s][0] = *(const bf16x8*)hs;
        A[0][s][1] = *(const bf16x8*)(hs + 32);
        const u16* hd = &hbf[(size_t)dv[s] * HD + 8 * g];
        A[1][s][0] = *(const bf16x8*)hd;
        A[1][s][1] = *(const bf16x8*)(hd + 32);
        const u16* ep = &eab[(base + 16 * s + c) * HD + 8 * g];
        A[2][s][0] = *(const bf16x8*)ep;
        A[2][s][1] = *(const bf16x8*)(ep + 32);
    }
    f32x4 acc[2][4];
    #pragma unroll
    for (int s = 0; s < 2; s++)
        #pragma unroll
        for (int tt = 0; tt < 4; tt++) {
            float bv = b1[tt * 16 + c];
            acc[s][tt] = (f32x4){bv, bv, bv, bv};
        }
    #pragma unroll
    for (int sec = 0; sec < 3; sec++)
        #pragma unroll
        for (int ki = 0; ki < 2; ki++)
            #pragma unroll
            for (int tt = 0; tt < 4; tt++) {
                bf16x8 bw = *(const bf16x8*)&w1t[(tt * 16 + c) * 192 + sec * 64 + ki * 32 + 8 * g];
                acc[0][tt] = __builtin_amdgcn_mfma_f32_16x16x32_bf16(A[sec][0][ki], bw, acc[0][tt], 0, 0, 0);
                acc[1][tt] = __builtin_amdgcn_mfma_f32_16x16x32_bf16(A[sec][1][ki], bw, acc[1][tt], 0, 0, 0);
            }
    #pragma unroll
    for (int s = 0; s < 2; s++)
        #pragma unroll
        for (int tt = 0; tt < 4; tt++)
            #pragma unroll
            for (int r = 0; r < 4; r++)
                sOw[(16 * s + 4 * g + r) * 72 + tt * 16 + c] = f2b(fmaxf(acc[s][tt][r], 0.f));
    WAVE_SYNC();
    bf16x8 A2[2][2];
    #pragma unroll
    for (int s = 0; s < 2; s++) {
        A2[s][0] = *(const bf16x8*)&sOw[(16 * s + c) * 72 + 8 * g];
        A2[s][1] = *(const bf16x8*)&sOw[(16 * s + c) * 72 + 32 + 8 * g];
    }
    WAVE_SYNC();
    #pragma unroll
    for (int s = 0; s < 2; s++)
        #pragma unroll
        for (int tt = 0; tt < 4; tt++) {
            float bv = b2[tt * 16 + c];
            acc2[s][tt] = (f32x4){bv, bv, bv, bv};
        }
    #pragma unroll
    for (int ki = 0; ki < 2; ki++)
        #pragma unroll
        for (int tt = 0; tt < 4; tt++) {
            bf16x8 bw = *(const bf16x8*)&w2t[(tt * 16 + c) * HD + ki * 32 + 8 * g];
            acc2[0][tt] = __builtin_amdgcn_mfma_f32_16x16x32_bf16(A2[0][ki], bw, acc2[0][tt], 0, 0, 0);
            acc2[1][tt] = __builtin_amdgcn_mfma_f32_16x16x32_bf16(A2[1][ki], bw, acc2[1][tt], 0, 0, 0);
        }
}

// ---------------- K6a: edge_upd layer0 FUSED with gine_msg layer1
__global__ __launch_bounds__(256) void k_edge_upd_fused(
    const u16* __restrict__ hbf, u16* __restrict__ eab,
    const int* __restrict__ src, const int* __restrict__ dst,
    const u16* __restrict__ w1t, const float* __restrict__ b1,
    const u16* __restrict__ w2t, const float* __restrict__ b2,
    const float* __restrict__ h, const u16* __restrict__ welt,
    const float* __restrict__ belin, float* __restrict__ agg)
{
    __shared__ u16 sO[4][32 * 72];   // 18 KB
    const int lane = threadIdx.x & 63, wv = threadIdx.x >> 6;
    const size_t base = ((size_t)blockIdx.x * 4 + wv) * 32;
    if (base >= NE) return;
    u16* sOw = sO[wv];
    const int c = lane & 15, g = lane >> 4;

    f32x4 acc2[2][4];
    edge_mlp_core(hbf, eab, src, dst, w1t, b1, w2t, b2, sOw, base, c, g, acc2);

    // ---- eab_new = bf16(eab + 0.5*upd): store global + LDS (for transpose) ----
    #pragma unroll
    for (int s = 0; s < 2; s++)
        #pragma unroll
        for (int tt = 0; tt < 4; tt++)
            #pragma unroll
            for (int r = 0; r < 4; r++) {
                size_t a = (base + 16 * s + 4 * g + r) * HD + tt * 16 + c;
                u16 nb = f2b(b2f(eab[a]) + 0.5f * acc2[s][tt][r]);
                eab[a] = nb;
                sOw[(16 * s + 4 * g + r) * 72 + tt * 16 + c] = nb;
            }
    WAVE_SYNC();

    // ---- fused gine_msg (layer 1): msg = relu(h[src] + eab_new @ welt + belin) ----
    bf16x8 A3[2][2];
    #pragma unroll
    for (int s = 0; s < 2; s++) {
        A3[s][0] = *(const bf16x8*)&sOw[(16 * s + c) * 72 + 8 * g];
        A3[s][1] = *(const bf16x8*)&sOw[(16 * s + c) * 72 + 32 + 8 * g];
    }
    f32x4 acc3[2][4];
    #pragma unroll
    for (int s = 0; s < 2; s++)
        #pragma unroll
        for (int tt = 0; tt < 4; tt++) {
            float bv = belin[tt * 16 + c];
            acc3[s][tt] = (f32x4){bv, bv, bv, bv};
        }
    #pragma unroll
    for (int ki = 0; ki < 2; ki++)
        #pragma unroll
        for (int tt = 0; tt < 4; tt++) {
            bf16x8 bw = *(const bf16x8*)&welt[(tt * 16 + c) * HD + ki * 32 + 8 * g];
            acc3[0][tt] = __builtin_amdgcn_mfma_f32_16x16x32_bf16(A3[0][ki], bw, acc3[0][tt], 0, 0, 0);
            acc3[1][tt] = __builtin_amdgcn_mfma_f32_16x16x32_bf16(A3[1][ki], bw, acc3[1][tt], 0, 0, 0);
        }
    int sv2[2][4], dv2[2][4];
    #pragma unroll
    for (int s = 0; s < 2; s++)
        #pragma unroll
        for (int r = 0; r < 4; r++) {
            sv2[s][r] = src[base + 16 * s + 4 * g + r];
            dv2[s][r] = dst[base + 16 * s + 4 * g + r];
        }
    #pragma unroll
    for (int s = 0; s < 2; s++)
        #pragma unroll
        for (int tt = 0; tt < 4; tt++)
            #pragma unroll
            for (int r = 0; r < 4; r++) {
                float m = acc3[s][tt][r] + h[(size_t)sv2[s][r] * HD + tt * 16 + c];
                m = fmaxf(m, 0.f);
                unsafeAtomicAdd(&agg[(size_t)dv2[s][r] * HD + tt * 16 + c], m);
            }
}

// ---------------- K6b: edge_upd layer1 FINAL: f32 output to d_out
__global__ __launch_bounds__(256) void k_edge_upd_final(
    const u16* __restrict__ hbf, const u16* __restrict__ eab,
    float* __restrict__ eaout,
    const int* __restrict__ src, const int* __restrict__ dst,
    const u16* __restrict__ w1t, const float* __restrict__ b1,
    const u16* __restrict__ w2t, const float* __restrict__ b2)
{
    __shared__ u16 sO[4][32 * 72];   // 18 KB
    const int lane = threadIdx.x & 63, wv = threadIdx.x >> 6;
    const size_t base = ((size_t)blockIdx.x * 4 + wv) * 32;
    if (base >= NE) return;
    u16* sOw = sO[wv];
    const int c = lane & 15, g = lane >> 4;

    f32x4 acc2[2][4];
    edge_mlp_core(hbf, eab, src, dst, w1t, b1, w2t, b2, sOw, base, c, g, acc2);

    #pragma unroll
    for (int s = 0; s < 2; s++)
        #pragma unroll
        for (int tt = 0; tt < 4; tt++)
            #pragma unroll
            for (int r = 0; r < 4; r++) {
                size_t a = (base + 16 * s + 4 * g + r) * HD + tt * 16 + c;
                eaout[a] = b2f(eab[a]) + 0.5f * acc2[s][tt][r];
            }
}

extern "C" void kernel_launch(void* const* d_in, const int* in_sizes, int n_in,
                              void* d_out, int out_size, void* d_ws, size_t ws_size,
                              hipStream_t stream)
{
    const float* x        = (const float*)d_in[0];
    const int*   ei       = (const int*)d_in[1];
    const float* eattr    = (const float*)d_in[2];
    const float* node_W   = (const float*)d_in[3];
    const float* node_b   = (const float*)d_in[4];
    const float* edge_W   = (const float*)d_in[5];
    const float* edge_b   = (const float*)d_in[6];
    const float* elin_W   = (const float*)d_in[7];
    const float* elin_b   = (const float*)d_in[8];
    const float* mlp1_W   = (const float*)d_in[9];
    const float* mlp1_b   = (const float*)d_in[10];
    const float* mlp2_W   = (const float*)d_in[11];
    const float* mlp2_b   = (const float*)d_in[12];
    const float* emlp1_W  = (const float*)d_in[13];
    const float* emlp1_b  = (const float*)d_in[14];
    const float* emlp2_W  = (const float*)d_in[15];
    const float* emlp2_b  = (const float*)d_in[16];
    const float* bn_gamma = (const float*)d_in[17];
    const float* bn_beta  = (const float*)d_in[18];

    // OUTPUT IS FLOAT32: h at [0, 3.2M), ea at [3.2M, 67.2M)
    float* hout = (float*)d_out;
    float* eaout = hout + (size_t)NN * HD;

    const int* src = ei;          // edge_index row-major (2, NE)
    const int* dst = ei + NE;

    float* hbuf = (float*)d_ws;
    float* agg  = hbuf + (size_t)NN * HD;
    float* out2 = agg + (size_t)NN * HD;
    float* bnst = out2 + (size_t)NN * HD;
    u16*   w1t  = (u16*)(bnst + 128);          // [2][64][192] bf16
    u16*   w2t  = w1t + 2 * 192 * HD;          // [2][64][64]  bf16
    u16*   welt = w2t + 2 * HD * HD;           // [2][64][64]  bf16 (elin)
    u16*   hbf  = welt + 2 * HD * HD;          // [NN][64] bf16
    u16*   eab  = hbf + (size_t)NN * HD;       // [NE][64] bf16 (128 MB)
    size_t base_need = ((size_t)NN * HD * 3 + 128) * sizeof(float)
                     + (2 * 192 * HD + 4 * HD * HD + (size_t)NN * HD
                        + (size_t)NE * HD) * sizeof(u16);

    // ---- host-side sanity sentinels (decodable through absmax) ----
    static const int exp_sizes[19] = {
        1600000, 2000000, 16000000, 2048, 64, 1024, 64,
        8192, 128, 8192, 128, 8192, 128, 24576, 128, 8192, 128, 128, 128};
    float sentinel = 0.f;
    if (n_in != 19) sentinel = 6000.f;
    else {
        for (int i = 0; i < 19; i++)
            if (in_sizes[i] != exp_sizes[i]) { sentinel = 2000.f + 32.f * i; break; }
    }
    if (sentinel == 0.f && ws_size < base_need) sentinel = 7000.f;
    if (sentinel != 0.f) {
        k_fill<<<dim3((unsigned)(((size_t)NN * HD + 255) / 256)), dim3(256), 0, stream>>>(
            hout, sentinel, (size_t)NN * HD);
        k_fill<<<dim3((unsigned)(((size_t)NE * HD + 255) / 256)), dim3(256), 0, stream>>>(
            eaout, 0.f, (size_t)NE * HD);
        return;
    }

    dim3 b256(256);
    const unsigned EG  = (NE + 255) / 256;           // 3907
    const unsigned WG2 = (NE + 127) / 128;           // 7813 (4 waves x 32 edges)
    k_prep_w1<<<dim3((2 * 192 * HD + 255) / 256), b256, 0, stream>>>(emlp1_W, w1t);
    k_prep_w64<<<dim3((2 * HD * HD + 255) / 256), b256, 0, stream>>>(emlp2_W, w2t);
    k_prep_w64<<<dim3((2 * HD * HD + 255) / 256), b256, 0, stream>>>(elin_W, welt);
    k_node_proj<<<dim3((NN + 3) / 4), b256, 0, stream>>>(x, node_W, node_b, hbuf);
    k_edge_proj<<<dim3(EG), b256, 0, stream>>>(eattr, edge_W, edge_b, eab);

    // ---- layer 0 ----
    hipMemsetAsync(agg, 0, (size_t)NN * HD * sizeof(float), stream);
    hipMemsetAsync(bnst, 0, 128 * sizeof(float), stream);
    k_gine_msg_mfma<<<dim3(WG2), b256, 0, stream>>>(
        eab, hbuf, src, dst, welt, elin_b, agg);
    k_node_mlp<<<dim3((NN + 255) / 256), b256, 0, stream>>>(
        hbuf, agg, mlp1_W, mlp1_b, mlp2_W, mlp2_b, out2);
    k_bnstats<<<dim3(256), b256, 0, stream>>>(out2, bnst);
    k_bn_h<<<dim3((NN * HD + 255) / 256), b256, 0, stream>>>(
        out2, bnst, bn_gamma, bn_beta, hbuf, hbf, hout, 0);
    // edge_upd(0) + fused gine_msg(1)
    hipMemsetAsync(agg, 0, (size_t)NN * HD * sizeof(float), stream);
    hipMemsetAsync(bnst, 0, 128 * sizeof(float), stream);
    k_edge_upd_fused<<<dim3(WG2), b256, 0, stream>>>(
        hbf, eab, src, dst, w1t, emlp1_b, w2t, emlp2_b,
        hbuf, welt + (size_t)HD * HD, elin_b + HD, agg);

    // ---- layer 1 ----
    k_node_mlp<<<dim3((NN + 255) / 256), b256, 0, stream>>>(
        hbuf, agg, mlp1_W + HD * HD, mlp1_b + HD,
        mlp2_W + HD * HD, mlp2_b + HD, out2);
    k_bnstats<<<dim3(256), b256, 0, stream>>>(out2, bnst);
    k_bn_h<<<dim3((NN * HD + 255) / 256), b256, 0, stream>>>(
        out2, bnst, bn_gamma + HD, bn_beta + HD, hbuf, hbf, hout, 1);
    k_edge_upd_final<<<dim3(WG2), b256, 0, stream>>>(
        hbf, eab, eaout, src, dst,
        w1t + (size_t)192 * HD, emlp1_b + HD,
        w2t + (size_t)HD * HD, emlp2_b + HD);
}

// Round 19
// 1003.842 us; speedup vs baseline: 1.4628x; 1.0589x over previous
//
#include <hip/hip_runtime.h>
#include <hip/hip_bf16.h>

#define NN 50000
#define NE 1000000
#define NF 32
#define ED 16
#define HD 64
#define BN_EPS 1e-5f

typedef unsigned short u16;
typedef __attribute__((ext_vector_type(8))) short bf16x8;
typedef __attribute__((ext_vector_type(4))) float f32x4;

// wave-level LDS fence: ds ops complete + no compiler reordering (rule #18)
#define WAVE_SYNC() do { \
    asm volatile("s_waitcnt lgkmcnt(0)" ::: "memory"); \
    __builtin_amdgcn_sched_barrier(0); \
} while (0)

__device__ __forceinline__ u16 f2b(float x)
{
    __hip_bfloat16 b = __float2bfloat16(x);
    u16 u; __builtin_memcpy(&u, &b, 2); return u;
}
__device__ __forceinline__ float b2f(u16 u)
{
    uint v = (uint)u << 16; float f; __builtin_memcpy(&f, &v, 4); return f;
}

// ---------------- diag: fill an f32 region with a sentinel constant
__global__ __launch_bounds__(256) void k_fill(float* p, float v, size_t n)
{
    size_t i = (size_t)blockIdx.x * 256 + threadIdx.x;
    if (i < n) p[i] = v;
}

// rank-4 update: o += t * W[0:4][:]  (weights wave-uniform)
__device__ __forceinline__ void gemm4(float (&o)[HD], float4 t, const float* __restrict__ Wr)
{
    #pragma unroll
    for (int f = 0; f < HD; f++) o[f] = fmaf(t.x, Wr[f], o[f]);
    #pragma unroll
    for (int f = 0; f < HD; f++) o[f] = fmaf(t.y, Wr[HD + f], o[f]);
    #pragma unroll
    for (int f = 0; f < HD; f++) o[f] = fmaf(t.z, Wr[2 * HD + f], o[f]);
    #pragma unroll
    for (int f = 0; f < HD; f++) o[f] = fmaf(t.w, Wr[3 * HD + f], o[f]);
}

// pack 8 consecutive f32 -> bf16x8 fragment (in registers)
__device__ __forceinline__ bf16x8 pack8(const float* __restrict__ p)
{
    float4 v0 = ((const float4*)p)[0];
    float4 v1 = ((const float4*)p)[1];
    union { uint u[4]; bf16x8 v; } r;
    r.u[0] = (uint)f2b(v0.x) | ((uint)f2b(v0.y) << 16);
    r.u[1] = (uint)f2b(v0.z) | ((uint)f2b(v0.w) << 16);
    r.u[2] = (uint)f2b(v1.x) | ((uint)f2b(v1.y) << 16);
    r.u[3] = (uint)f2b(v1.z) | ((uint)f2b(v1.w) << 16);
    return r.v;
}

// ---------------- prep: W1[l][k][f] (f32) -> w1t[l][f][k] (bf16), k=0..191
__global__ __launch_bounds__(256) void k_prep_w1(const float* __restrict__ W, u16* __restrict__ out)
{
    int idx = blockIdx.x * 256 + threadIdx.x;
    if (idx >= 2 * 192 * HD) return;
    int l = idx / (192 * HD), r = idx % (192 * HD), k = r / HD, f = r % HD;
    out[l * 192 * HD + f * 192 + k] = f2b(W[idx]);
}
// ---------------- prep: 2 layers of [64][64] (k,f) -> (f,k) bf16
__global__ __launch_bounds__(256) void k_prep_w64(const float* __restrict__ W, u16* __restrict__ out)
{
    int idx = blockIdx.x * 256 + threadIdx.x;
    if (idx >= 2 * HD * HD) return;
    int l = idx / (HD * HD), r = idx % (HD * HD), k = r / HD, f = r % HD;
    out[l * HD * HD + f * HD + k] = f2b(W[idx]);
}
// ---------------- prep: edge_W [16][64] (k,f) -> padded [64][32] (f,k), k>=16 -> 0
__global__ __launch_bounds__(256) void k_prep_wpad(const float* __restrict__ W, u16* __restrict__ out)
{
    int idx = blockIdx.x * 256 + threadIdx.x;
    if (idx >= HD * 32) return;
    int f = idx / 32, k = idx % 32;
    out[f * 32 + k] = (k < ED) ? f2b(W[k * HD + f]) : (u16)0;
}

// ---------------- K1: h = x @ node_W + node_b  (wave per node, K=32 via shfl)
__global__ __launch_bounds__(256) void k_node_proj(
    const float* __restrict__ x, const float* __restrict__ W,
    const float* __restrict__ b, float* __restrict__ h)
{
    __shared__ float sW[NF * HD];   // 8 KB
    for (int t = threadIdx.x; t < NF * HD; t += 256) sW[t] = W[t];
    __syncthreads();
    int lane = threadIdx.x & 63, wv = threadIdx.x >> 6;
    int n = blockIdx.x * 4 + wv;
    if (n >= NN) return;
    float a = (lane < NF) ? x[(size_t)n * NF + lane] : 0.f;
    float acc = b[lane];
    #pragma unroll
    for (int k = 0; k < NF; k++) acc = fmaf(__shfl(a, k), sW[k * HD + lane], acc);
    h[(size_t)n * HD + lane] = acc;
}

// ---------------- K2+K3 FUSED: eab = bf16(attr@edge_W+b); msg = relu(h[src]+eab@welt+belin)
// 32 edges/wave; proj via MFMA (K=16 zero-padded to 32); atomic agg[dst]
__global__ __launch_bounds__(256) void k_edge_proj_gine(
    const float* __restrict__ attr, const float* __restrict__ h,
    const int* __restrict__ src, const int* __restrict__ dst,
    const u16* __restrict__ wpadt, const float* __restrict__ eb,
    const u16* __restrict__ welt, const float* __restrict__ belin,
    u16* __restrict__ eab, float* __restrict__ agg)
{
    __shared__ u16 sO[4][32 * 72];   // 18 KB
    const int lane = threadIdx.x & 63, wv = threadIdx.x >> 6;
    const size_t base = ((size_t)blockIdx.x * 4 + wv) * 32;
    if (base >= NE) return;
    u16* sOw = sO[wv];
    const int c = lane & 15, g = lane >> 4;

    // ---- epilogue data EARLY (issue h-gathers before MFMA chain) ----
    int sv2[2][4], dv2[2][4];
    #pragma unroll
    for (int s = 0; s < 2; s++)
        #pragma unroll
        for (int r = 0; r < 4; r++) {
            sv2[s][r] = src[base + 16 * s + 4 * g + r];
            dv2[s][r] = dst[base + 16 * s + 4 * g + r];
        }
    float hv[2][4][4];
    #pragma unroll
    for (int s = 0; s < 2; s++)
        #pragma unroll
        for (int tt = 0; tt < 4; tt++)
            #pragma unroll
            for (int r = 0; r < 4; r++)
                hv[s][tt][r] = h[(size_t)sv2[s][r] * HD + tt * 16 + c];

    // ---- A-frags from attr: K=16 real (g<2), zero else ----
    bf16x8 zero8 = {0, 0, 0, 0, 0, 0, 0, 0};
    bf16x8 ap[2];
    #pragma unroll
    for (int s = 0; s < 2; s++)
        ap[s] = (g < 2) ? pack8(attr + (base + 16 * s + c) * ED + 8 * g) : zero8;

    // ---- proj MFMA: ea = attr @ edge_W + eb ----
    f32x4 acc[2][4];
    #pragma unroll
    for (int s = 0; s < 2; s++)
        #pragma unroll
        for (int tt = 0; tt < 4; tt++) {
            float bv = eb[tt * 16 + c];
            acc[s][tt] = (f32x4){bv, bv, bv, bv};
        }
    #pragma unroll
    for (int tt = 0; tt < 4; tt++) {
        bf16x8 bw = *(const bf16x8*)&wpadt[(tt * 16 + c) * 32 + 8 * g];
        acc[0][tt] = __builtin_amdgcn_mfma_f32_16x16x32_bf16(ap[0], bw, acc[0][tt], 0, 0, 0);
        acc[1][tt] = __builtin_amdgcn_mfma_f32_16x16x32_bf16(ap[1], bw, acc[1][tt], 0, 0, 0);
    }
    // ---- write eab (global + LDS transpose) ----
    #pragma unroll
    for (int s = 0; s < 2; s++)
        #pragma unroll
        for (int tt = 0; tt < 4; tt++)
            #pragma unroll
            for (int r = 0; r < 4; r++) {
                u16 nb = f2b(acc[s][tt][r]);
                eab[(base + 16 * s + 4 * g + r) * HD + tt * 16 + c] = nb;
                sOw[(16 * s + 4 * g + r) * 72 + tt * 16 + c] = nb;
            }
    WAVE_SYNC();

    // ---- fused gine_msg(0): msg = relu(h[src] + eab @ welt + belin) ----
    bf16x8 A3[2][2];
    #pragma unroll
    for (int s = 0; s < 2; s++) {
        A3[s][0] = *(const bf16x8*)&sOw[(16 * s + c) * 72 + 8 * g];
        A3[s][1] = *(const bf16x8*)&sOw[(16 * s + c) * 72 + 32 + 8 * g];
    }
    f32x4 acc3[2][4];
    #pragma unroll
    for (int s = 0; s < 2; s++)
        #pragma unroll
        for (int tt = 0; tt < 4; tt++) {
            float bv = belin[tt * 16 + c];
            acc3[s][tt] = (f32x4){bv, bv, bv, bv};
        }
    #pragma unroll
    for (int ki = 0; ki < 2; ki++)
        #pragma unroll
        for (int tt = 0; tt < 4; tt++) {
            bf16x8 bw = *(const bf16x8*)&welt[(tt * 16 + c) * HD + ki * 32 + 8 * g];
            acc3[0][tt] = __builtin_amdgcn_mfma_f32_16x16x32_bf16(A3[0][ki], bw, acc3[0][tt], 0, 0, 0);
            acc3[1][tt] = __builtin_amdgcn_mfma_f32_16x16x32_bf16(A3[1][ki], bw, acc3[1][tt], 0, 0, 0);
        }
    #pragma unroll
    for (int s = 0; s < 2; s++)
        #pragma unroll
        for (int tt = 0; tt < 4; tt++)
            #pragma unroll
            for (int r = 0; r < 4; r++) {
                float m = fmaxf(acc3[s][tt][r] + hv[s][tt][r], 0.f);
                unsafeAtomicAdd(&agg[(size_t)dv2[s][r] * HD + tt * 16 + c], m);
            }
}

// ---------------- K4: out2 = mlp2(relu(mlp1(h+agg)))  (thread per node)
__global__ __launch_bounds__(256) void k_node_mlp(
    const float* __restrict__ h, const float* __restrict__ agg,
    const float* __restrict__ W1, const float* __restrict__ b1,
    const float* __restrict__ W2, const float* __restrict__ b2,
    float* __restrict__ out2)
{
    int n = blockIdx.x * 256 + threadIdx.x;
    if (n >= NN) return;
    float o[HD];
    #pragma unroll
    for (int f = 0; f < HD; f++) o[f] = b1[f];
    const float4* hr = (const float4*)(h + (size_t)n * HD);
    const float4* ar = (const float4*)(agg + (size_t)n * HD);
    #pragma unroll 4
    for (int k4 = 0; k4 < 16; k4++) {
        float4 t1 = hr[k4], t2 = ar[k4];
        float4 t = make_float4(t1.x + t2.x, t1.y + t2.y, t1.z + t2.z, t1.w + t2.w);
        gemm4(o, t, W1 + (k4 * 4) * HD);
    }
    #pragma unroll
    for (int k = 0; k < HD; k++) o[k] = fmaxf(o[k], 0.f);
    #pragma unroll
    for (int c = 0; c < 4; c++) {
        float p[16];
        #pragma unroll
        for (int j = 0; j < 16; j++) p[j] = b2[c * 16 + j];
        for (int k = 0; k < HD; k++) {
            const float* Wr = W2 + k * HD + c * 16;
            #pragma unroll
            for (int j = 0; j < 16; j++) p[j] = fmaf(o[k], Wr[j], p[j]);
        }
        float4* orow = (float4*)(out2 + (size_t)n * HD + c * 16);
        #pragma unroll
        for (int q = 0; q < 4; q++)
            orow[q] = make_float4(p[4*q], p[4*q+1], p[4*q+2], p[4*q+3]);
    }
}

// ---------------- K4b: BN stats reduction (lane = feature, coalesced rows)
__global__ __launch_bounds__(256) void k_bnstats(
    const float* __restrict__ out2, float* __restrict__ bnst)
{
    int f = threadIdx.x & 63;
    int row0 = blockIdx.x * 4 + (threadIdx.x >> 6);
    float s = 0.f, q = 0.f;
    for (int r = row0; r < NN; r += gridDim.x * 4) {
        float v = out2[(size_t)r * HD + f];
        s += v; q += v * v;
    }
    unsafeAtomicAdd(&bnst[f], s);
    unsafeAtomicAdd(&bnst[HD + f], q);
}

// ---------------- K5: BN + h = (h + relu(out2*sc+sh)) * 0.5 ; also bf16 h copy
__global__ __launch_bounds__(256) void k_bn_h(
    const float* __restrict__ out2, const float* __restrict__ bnst,
    const float* __restrict__ gamma, const float* __restrict__ beta,
    float* __restrict__ h, u16* __restrict__ hbf, float* __restrict__ hout, int last)
{
    size_t idx = (size_t)blockIdx.x * 256 + threadIdx.x;
    if (idx >= (size_t)NN * HD) return;
    int f = (int)(idx & 63);
    float mu  = bnst[f] * (1.f / NN);
    float var = bnst[HD + f] * (1.f / NN) - mu * mu;
    float sc  = gamma[f] * rsqrtf(var + BN_EPS);
    float sh  = beta[f] - mu * sc;
    float o   = fmaxf(fmaf(out2[idx], sc, sh), 0.f);
    float hn  = (h[idx] + o) * 0.5f;
    h[idx] = hn;
    hbf[idx] = f2b(hn);
    if (last) hout[idx] = hn;
}

// shared core: layer-1 + layer-2 MFMA for the edge MLP (32 edges/wave)
// returns acc2 (update, D layout). A-fragments direct from global bf16.
__device__ __forceinline__ void edge_mlp_core(
    const u16* __restrict__ hbf, const u16* __restrict__ eab,
    const int* __restrict__ src, const int* __restrict__ dst,
    const u16* __restrict__ w1t, const float* __restrict__ b1,
    const u16* __restrict__ w2t, const float* __restrict__ b2,
    u16* sOw, size_t base, int c, int g, f32x4 (&acc2)[2][4])
{
    int sv[2], dv[2];
    #pragma unroll
    for (int s = 0; s < 2; s++) {
        sv[s] = src[base + 16 * s + c];
        dv[s] = dst[base + 16 * s + c];
    }
    bf16x8 A[3][2][2];
    #pragma unroll
    for (int s = 0; s < 2; s++) {
        const u16* hs = &hbf[(size_t)sv[s] * HD + 8 * g];
        A[0][s][0] = *(const bf16x8*)hs;
        A[0][s][1] = *(const bf16x8*)(hs + 32);
        const u16* hd = &hbf[(size_t)dv[s] * HD + 8 * g];
        A[1][s][0] = *(const bf16x8*)hd;
        A[1][s][1] = *(const bf16x8*)(hd + 32);
        const u16* ep = &eab[(base + 16 * s + c) * HD + 8 * g];
        A[2][s][0] = *(const bf16x8*)ep;
        A[2][s][1] = *(const bf16x8*)(ep + 32);
    }
    f32x4 acc[2][4];
    #pragma unroll
    for (int s = 0; s < 2; s++)
        #pragma unroll
        for (int tt = 0; tt < 4; tt++) {
            float bv = b1[tt * 16 + c];
            acc[s][tt] = (f32x4){bv, bv, bv, bv};
        }
    #pragma unroll
    for (int sec = 0; sec < 3; sec++)
        #pragma unroll
        for (int ki = 0; ki < 2; ki++)
            #pragma unroll
            for (int tt = 0; tt < 4; tt++) {
                bf16x8 bw = *(const bf16x8*)&w1t[(tt * 16 + c) * 192 + sec * 64 + ki * 32 + 8 * g];
                acc[0][tt] = __builtin_amdgcn_mfma_f32_16x16x32_bf16(A[sec][0][ki], bw, acc[0][tt], 0, 0, 0);
                acc[1][tt] = __builtin_amdgcn_mfma_f32_16x16x32_bf16(A[sec][1][ki], bw, acc[1][tt], 0, 0, 0);
            }
    #pragma unroll
    for (int s = 0; s < 2; s++)
        #pragma unroll
        for (int tt = 0; tt < 4; tt++)
            #pragma unroll
            for (int r = 0; r < 4; r++)
                sOw[(16 * s + 4 * g + r) * 72 + tt * 16 + c] = f2b(fmaxf(acc[s][tt][r], 0.f));
    WAVE_SYNC();
    bf16x8 A2[2][2];
    #pragma unroll
    for (int s = 0; s < 2; s++) {
        A2[s][0] = *(const bf16x8*)&sOw[(16 * s + c) * 72 + 8 * g];
        A2[s][1] = *(const bf16x8*)&sOw[(16 * s + c) * 72 + 32 + 8 * g];
    }
    WAVE_SYNC();
    #pragma unroll
    for (int s = 0; s < 2; s++)
        #pragma unroll
        for (int tt = 0; tt < 4; tt++) {
            float bv = b2[tt * 16 + c];
            acc2[s][tt] = (f32x4){bv, bv, bv, bv};
        }
    #pragma unroll
    for (int ki = 0; ki < 2; ki++)
        #pragma unroll
        for (int tt = 0; tt < 4; tt++) {
            bf16x8 bw = *(const bf16x8*)&w2t[(tt * 16 + c) * HD + ki * 32 + 8 * g];
            acc2[0][tt] = __builtin_amdgcn_mfma_f32_16x16x32_bf16(A2[0][ki], bw, acc2[0][tt], 0, 0, 0);
            acc2[1][tt] = __builtin_amdgcn_mfma_f32_16x16x32_bf16(A2[1][ki], bw, acc2[1][tt], 0, 0, 0);
        }
}

// ---------------- K6a: edge_upd layer0 FUSED with gine_msg layer1 (early gathers)
__global__ __launch_bounds__(256) void k_edge_upd_fused(
    const u16* __restrict__ hbf, u16* __restrict__ eab,
    const int* __restrict__ src, const int* __restrict__ dst,
    const u16* __restrict__ w1t, const float* __restrict__ b1,
    const u16* __restrict__ w2t, const float* __restrict__ b2,
    const float* __restrict__ h, const u16* __restrict__ welt,
    const float* __restrict__ belin, float* __restrict__ agg)
{
    __shared__ u16 sO[4][32 * 72];   // 18 KB
    const int lane = threadIdx.x & 63, wv = threadIdx.x >> 6;
    const size_t base = ((size_t)blockIdx.x * 4 + wv) * 32;
    if (base >= NE) return;
    u16* sOw = sO[wv];
    const int c = lane & 15, g = lane >> 4;

    // ---- epilogue data EARLY: indices, h-gathers, old eab (D layout) ----
    int sv2[2][4], dv2[2][4];
    #pragma unroll
    for (int s = 0; s < 2; s++)
        #pragma unroll
        for (int r = 0; r < 4; r++) {
            sv2[s][r] = src[base + 16 * s + 4 * g + r];
            dv2[s][r] = dst[base + 16 * s + 4 * g + r];
        }
    u16 eold[2][4][4];
    #pragma unroll
    for (int s = 0; s < 2; s++)
        #pragma unroll
        for (int tt = 0; tt < 4; tt++)
            #pragma unroll
            for (int r = 0; r < 4; r++)
                eold[s][tt][r] = eab[(base + 16 * s + 4 * g + r) * HD + tt * 16 + c];
    float hv[2][4][4];
    #pragma unroll
    for (int s = 0; s < 2; s++)
        #pragma unroll
        for (int tt = 0; tt < 4; tt++)
            #pragma unroll
            for (int r = 0; r < 4; r++)
                hv[s][tt][r] = h[(size_t)sv2[s][r] * HD + tt * 16 + c];

    f32x4 acc2[2][4];
    edge_mlp_core(hbf, eab, src, dst, w1t, b1, w2t, b2, sOw, base, c, g, acc2);

    // ---- eab_new = bf16(eab + 0.5*upd): store global + LDS (for transpose) ----
    #pragma unroll
    for (int s = 0; s < 2; s++)
        #pragma unroll
        for (int tt = 0; tt < 4; tt++)
            #pragma unroll
            for (int r = 0; r < 4; r++) {
                size_t a = (base + 16 * s + 4 * g + r) * HD + tt * 16 + c;
                u16 nb = f2b(b2f(eold[s][tt][r]) + 0.5f * acc2[s][tt][r]);
                eab[a] = nb;
                sOw[(16 * s + 4 * g + r) * 72 + tt * 16 + c] = nb;
            }
    WAVE_SYNC();

    // ---- fused gine_msg (layer 1): msg = relu(h[src] + eab_new @ welt + belin) ----
    bf16x8 A3[2][2];
    #pragma unroll
    for (int s = 0; s < 2; s++) {
        A3[s][0] = *(const bf16x8*)&sOw[(16 * s + c) * 72 + 8 * g];
        A3[s][1] = *(const bf16x8*)&sOw[(16 * s + c) * 72 + 32 + 8 * g];
    }
    f32x4 acc3[2][4];
    #pragma unroll
    for (int s = 0; s < 2; s++)
        #pragma unroll
        for (int tt = 0; tt < 4; tt++) {
            float bv = belin[tt * 16 + c];
            acc3[s][tt] = (f32x4){bv, bv, bv, bv};
        }
    #pragma unroll
    for (int ki = 0; ki < 2; ki++)
        #pragma unroll
        for (int tt = 0; tt < 4; tt++) {
            bf16x8 bw = *(const bf16x8*)&welt[(tt * 16 + c) * HD + ki * 32 + 8 * g];
            acc3[0][tt] = __builtin_amdgcn_mfma_f32_16x16x32_bf16(A3[0][ki], bw, acc3[0][tt], 0, 0, 0);
            acc3[1][tt] = __builtin_amdgcn_mfma_f32_16x16x32_bf16(A3[1][ki], bw, acc3[1][tt], 0, 0, 0);
        }
    #pragma unroll
    for (int s = 0; s < 2; s++)
        #pragma unroll
        for (int tt = 0; tt < 4; tt++)
            #pragma unroll
            for (int r = 0; r < 4; r++) {
                float m = fmaxf(acc3[s][tt][r] + hv[s][tt][r], 0.f);
                unsafeAtomicAdd(&agg[(size_t)dv2[s][r] * HD + tt * 16 + c], m);
            }
}

// ---------------- K6b: edge_upd layer1 FINAL: f32 output to d_out (early eold)
__global__ __launch_bounds__(256) void k_edge_upd_final(
    const u16* __restrict__ hbf, const u16* __restrict__ eab,
    float* __restrict__ eaout,
    const int* __restrict__ src, const int* __restrict__ dst,
    const u16* __restrict__ w1t, const float* __restrict__ b1,
    const u16* __restrict__ w2t, const float* __restrict__ b2)
{
    __shared__ u16 sO[4][32 * 72];   // 18 KB
    const int lane = threadIdx.x & 63, wv = threadIdx.x >> 6;
    const size_t base = ((size_t)blockIdx.x * 4 + wv) * 32;
    if (base >= NE) return;
    u16* sOw = sO[wv];
    const int c = lane & 15, g = lane >> 4;

    u16 eold[2][4][4];
    #pragma unroll
    for (int s = 0; s < 2; s++)
        #pragma unroll
        for (int tt = 0; tt < 4; tt++)
            #pragma unroll
            for (int r = 0; r < 4; r++)
                eold[s][tt][r] = eab[(base + 16 * s + 4 * g + r) * HD + tt * 16 + c];

    f32x4 acc2[2][4];
    edge_mlp_core(hbf, eab, src, dst, w1t, b1, w2t, b2, sOw, base, c, g, acc2);

    #pragma unroll
    for (int s = 0; s < 2; s++)
        #pragma unroll
        for (int tt = 0; tt < 4; tt++)
            #pragma unroll
            for (int r = 0; r < 4; r++) {
                size_t a = (base + 16 * s + 4 * g + r) * HD + tt * 16 + c;
                eaout[a] = b2f(eold[s][tt][r]) + 0.5f * acc2[s][tt][r];
            }
}

extern "C" void kernel_launch(void* const* d_in, const int* in_sizes, int n_in,
                              void* d_out, int out_size, void* d_ws, size_t ws_size,
                              hipStream_t stream)
{
    const float* x        = (const float*)d_in[0];
    const int*   ei       = (const int*)d_in[1];
    const float* eattr    = (const float*)d_in[2];
    const float* node_W   = (const float*)d_in[3];
    const float* node_b   = (const float*)d_in[4];
    const float* edge_W   = (const float*)d_in[5];
    const float* edge_b   = (const float*)d_in[6];
    const float* elin_W   = (const float*)d_in[7];
    const float* elin_b   = (const float*)d_in[8];
    const float* mlp1_W   = (const float*)d_in[9];
    const float* mlp1_b   = (const float*)d_in[10];
    const float* mlp2_W   = (const float*)d_in[11];
    const float* mlp2_b   = (const float*)d_in[12];
    const float* emlp1_W  = (const float*)d_in[13];
    const float* emlp1_b  = (const float*)d_in[14];
    const float* emlp2_W  = (const float*)d_in[15];
    const float* emlp2_b  = (const float*)d_in[16];
    const float* bn_gamma = (const float*)d_in[17];
    const float* bn_beta  = (const float*)d_in[18];

    // OUTPUT IS FLOAT32: h at [0, 3.2M), ea at [3.2M, 67.2M)
    float* hout = (float*)d_out;
    float* eaout = hout + (size_t)NN * HD;

    const int* src = ei;          // edge_index row-major (2, NE)
    const int* dst = ei + NE;

    float* hbuf = (float*)d_ws;
    float* agg  = hbuf + (size_t)NN * HD;
    float* out2 = agg + (size_t)NN * HD;
    float* bnst = out2 + (size_t)NN * HD;
    u16*   w1t  = (u16*)(bnst + 128);          // [2][64][192] bf16
    u16*   w2t  = w1t + 2 * 192 * HD;          // [2][64][64]  bf16
    u16*   welt = w2t + 2 * HD * HD;           // [2][64][64]  bf16 (elin)
    u16*   wpad = welt + 2 * HD * HD;          // [64][32]     bf16 (edge proj, padded)
    u16*   hbf  = wpad + HD * 32;              // [NN][64] bf16
    u16*   eab  = hbf + (size_t)NN * HD;       // [NE][64] bf16 (128 MB)
    size_t base_need = ((size_t)NN * HD * 3 + 128) * sizeof(float)
                     + (2 * 192 * HD + 4 * HD * HD + HD * 32 + (size_t)NN * HD
                        + (size_t)NE * HD) * sizeof(u16);

    // ---- host-side sanity sentinels (decodable through absmax) ----
    static const int exp_sizes[19] = {
        1600000, 2000000, 16000000, 2048, 64, 1024, 64,
        8192, 128, 8192, 128, 8192, 128, 24576, 128, 8192, 128, 128, 128};
    float sentinel = 0.f;
    if (n_in != 19) sentinel = 6000.f;
    else {
        for (int i = 0; i < 19; i++)
            if (in_sizes[i] != exp_sizes[i]) { sentinel = 2000.f + 32.f * i; break; }
    }
    if (sentinel == 0.f && ws_size < base_need) sentinel = 7000.f;
    if (sentinel != 0.f) {
        k_fill<<<dim3((unsigned)(((size_t)NN * HD + 255) / 256)), dim3(256), 0, stream>>>(
            hout, sentinel, (size_t)NN * HD);
        k_fill<<<dim3((unsigned)(((size_t)NE * HD + 255) / 256)), dim3(256), 0, stream>>>(
            eaout, 0.f, (size_t)NE * HD);
        return;
    }

    dim3 b256(256);
    const unsigned WG2 = (NE + 127) / 128;           // 7813 (4 waves x 32 edges)
    k_prep_w1<<<dim3((2 * 192 * HD + 255) / 256), b256, 0, stream>>>(emlp1_W, w1t);
    k_prep_w64<<<dim3((2 * HD * HD + 255) / 256), b256, 0, stream>>>(emlp2_W, w2t);
    k_prep_w64<<<dim3((2 * HD * HD + 255) / 256), b256, 0, stream>>>(elin_W, welt);
    k_prep_wpad<<<dim3((HD * 32 + 255) / 256), b256, 0, stream>>>(edge_W, wpad);
    k_node_proj<<<dim3((NN + 3) / 4), b256, 0, stream>>>(x, node_W, node_b, hbuf);

    // ---- layer 0: fused edge_proj + gine_msg(0) ----
    hipMemsetAsync(agg, 0, (size_t)NN * HD * sizeof(float), stream);
    hipMemsetAsync(bnst, 0, 128 * sizeof(float), stream);
    k_edge_proj_gine<<<dim3(WG2), b256, 0, stream>>>(
        eattr, hbuf, src, dst, wpad, edge_b, welt, elin_b, eab, agg);
    k_node_mlp<<<dim3((NN + 255) / 256), b256, 0, stream>>>(
        hbuf, agg, mlp1_W, mlp1_b, mlp2_W, mlp2_b, out2);
    k_bnstats<<<dim3(256), b256, 0, stream>>>(out2, bnst);
    k_bn_h<<<dim3((NN * HD + 255) / 256), b256, 0, stream>>>(
        out2, bnst, bn_gamma, bn_beta, hbuf, hbf, hout, 0);
    // edge_upd(0) + fused gine_msg(1)
    hipMemsetAsync(agg, 0, (size_t)NN * HD * sizeof(float), stream);
    hipMemsetAsync(bnst, 0, 128 * sizeof(float), stream);
    k_edge_upd_fused<<<dim3(WG2), b256, 0, stream>>>(
        hbf, eab, src, dst, w1t, emlp1_b, w2t, emlp2_b,
        hbuf, welt + (size_t)HD * HD, elin_b + HD, agg);

    // ---- layer 1 ----
    k_node_mlp<<<dim3((NN + 255) / 256), b256, 0, stream>>>(
        hbuf, agg, mlp1_W + HD * HD, mlp1_b + HD,
        mlp2_W + HD * HD, mlp2_b + HD, out2);
    k_bnstats<<<dim3(256), b256, 0, stream>>>(out2, bnst);
    k_bn_h<<<dim3((NN * HD + 255) / 256), b256, 0, stream>>>(
        out2, bnst, bn_gamma + HD, bn_beta + HD, hbuf, hbf, hout, 1);
    k_edge_upd_final<<<dim3(WG2), b256, 0, stream>>>(
        hbf, eab, eaout, src, dst,
        w1t + (size_t)192 * HD, emlp1_b + HD,
        w2t + (size_t)HD * HD, emlp2_b + HD);
}